// Round 2
// baseline (276.131 us; speedup 1.0000x reference)
//
#include <hip/hip_runtime.h>

#define T_DIM 64
#define N_DIM 2000
#define C_DIM 64
#define E_DIM 32000
#define ROWS (T_DIM * N_DIM)   // 128000
#define BN_EPS 1e-5f

typedef short s8v __attribute__((ext_vector_type(8)));
typedef float f4v __attribute__((ext_vector_type(4)));

__device__ __forceinline__ ushort f2b(float f) {
    unsigned u = __float_as_uint(f);
    unsigned r = u + 0x7FFF + ((u >> 16) & 1);
    return (ushort)(r >> 16);
}
__device__ __forceinline__ float b2f(ushort h) {
    return __uint_as_float(((unsigned)h) << 16);
}

// ---------------- prep kernels ----------------

__global__ void k_deg(const int* __restrict__ ei, int* __restrict__ deg) {
    int e = blockIdx.x * 256 + threadIdx.x;
    if (e < E_DIM) atomicAdd(&deg[ei[E_DIM + e]], 1);
}

// exclusive prefix sum of (deg[n]+1) -> offs[0..N_DIM], plus fused dinv,
// self-edge slot-0 write, and cursor init.
__global__ void k_scan(const int* __restrict__ deg, int* __restrict__ offs,
                       float* __restrict__ dinv, int* __restrict__ cursor,
                       int2* __restrict__ edat) {
    __shared__ int a[2048], b[2048];
    int tid = threadIdx.x;
    for (int i = tid; i < 2048; i += 1024) a[i] = (i < N_DIM) ? (deg[i] + 1) : 0;
    __syncthreads();
    int* s = a; int* d = b;
    for (int off = 1; off < 2048; off <<= 1) {
        for (int i = tid; i < 2048; i += 1024)
            d[i] = s[i] + ((i >= off) ? s[i - off] : 0);
        __syncthreads();
        int* t = s; s = d; d = t;
    }
    for (int i = tid; i < 2048; i += 1024)
        if (i <= N_DIM) offs[i] = (i == 0) ? 0 : s[i - 1];
    for (int n = tid; n < N_DIM; n += 1024) {
        float dn = rsqrtf((float)(deg[n] + 1));  // +1 self-loop
        dinv[n] = dn;
        int o = (n == 0) ? 0 : s[n - 1];
        edat[o] = make_int2(n, __float_as_int(dn * dn));
        cursor[n] = 1;
    }
}

__global__ void k_fill(const int* __restrict__ ei, const int* __restrict__ offs,
                       const float* __restrict__ dinv, int* __restrict__ cursor,
                       int2* __restrict__ edat) {
    int e = blockIdx.x * 256 + threadIdx.x;
    if (e < E_DIM) {
        int s = ei[e];
        int d = ei[E_DIM + e];
        int p = atomicAdd(&cursor[d], 1);
        edat[offs[d] + p] = make_int2(s, __float_as_int(dinv[s] * dinv[d]));
    }
}

// W1p[j][i][c] = (C1_j @ gw)[i,c]  (fp32, plain layout); b1c = c1b @ gw
__global__ void k_wprep(const float* __restrict__ c1w, const float* __restrict__ c1b,
                        const float* __restrict__ gw,
                        float* __restrict__ W1p, float* __restrict__ b1c) {
    int gid = blockIdx.x * 256 + threadIdx.x;   // 48*256 = 12288
    if (gid < 12288) {
        int j = gid / 4096, rem = gid & 4095, i = rem >> 6, c = rem & 63;
        float s = 0.f;
        for (int o = 0; o < 64; ++o)
            s += c1w[o * 192 + i * 3 + j] * gw[o * 64 + c];
        W1p[(j * 64 + i) * 64 + c] = s;
        if (gid < 64) {
            float bs = 0.f;
            for (int o = 0; o < 64; ++o) bs += c1b[o] * gw[o * 64 + gid];
            b1c[gid] = bs;
        }
    }
}

// Fused conv5 weights: W5_m = sum_{j+k=m, k in K2(class)} W1_j @ C2_k
// class 0 = interior (all k), 1 = t==0 (k>=1), 2 = t==63 (k<=1).
// Stored bf16 in MFMA B-frag order for K=320: kk = m*64 + i,
//   flat = (((kk>>5)*4 + (n>>4))*64 + ((kk>>3)&3)*16 + (n&15))*8 + (kk&7)  (< 20480)
// Also per-class biases: bz = sum_k W2_k^T b1c ; beta = sum_k W2_k^T gcn_b + c2b.
__global__ void k_wprep5(const float* __restrict__ W1p, const float* __restrict__ b1c,
                         const float* __restrict__ gcn_b, const float* __restrict__ c2b,
                         const float* __restrict__ c2w,
                         ushort* __restrict__ W5f, float* __restrict__ bz,
                         float* __restrict__ beta) {
    int gid = blockIdx.x * 256 + threadIdx.x;   // 16*256 = 4096
    int i = gid >> 6, n = gid & 63;
    float d[3][3] = {{0.f,0.f,0.f},{0.f,0.f,0.f},{0.f,0.f,0.f}};
    for (int c = 0; c < 64; ++c) {
        float a0 = W1p[(0 * 64 + i) * 64 + c];
        float a1 = W1p[(1 * 64 + i) * 64 + c];
        float a2 = W1p[(2 * 64 + i) * 64 + c];
        float b0 = c2w[n * 192 + c * 3 + 0];
        float b1 = c2w[n * 192 + c * 3 + 1];
        float b2 = c2w[n * 192 + c * 3 + 2];
        d[0][0] += a0 * b0; d[0][1] += a0 * b1; d[0][2] += a0 * b2;
        d[1][0] += a1 * b0; d[1][1] += a1 * b1; d[1][2] += a1 * b2;
        d[2][0] += a2 * b0; d[2][1] += a2 * b1; d[2][2] += a2 * b2;
    }
    for (int cls = 0; cls < 3; ++cls) {
        for (int m = 0; m < 5; ++m) {
            float w = 0.f;
            for (int j = 0; j < 3; ++j) {
                int k = m - j;
                if (k < 0 || k > 2) continue;
                if (cls == 1 && k == 0) continue;
                if (cls == 2 && k == 2) continue;
                w += d[j][k];
            }
            int kk = m * 64 + i;
            int flat = (((kk >> 5) * 4 + (n >> 4)) * 64 + ((kk >> 3) & 3) * 16 + (n & 15)) * 8 + (kk & 7);
            W5f[cls * 20480 + flat] = f2b(w);
        }
    }
    if (i == 0) {
        for (int cls = 0; cls < 3; ++cls) {
            float s1 = 0.f, s2 = 0.f;
            for (int k = 0; k < 3; ++k) {
                if (cls == 1 && k == 0) continue;
                if (cls == 2 && k == 2) continue;
                for (int c = 0; c < 64; ++c) {
                    float w2 = c2w[n * 192 + c * 3 + k];
                    s1 += b1c[c] * w2;
                    s2 += gcn_b[c] * w2;
                }
            }
            bz[cls * 64 + n] = s1;
            beta[cls * 64 + n] = s2 + c2b[n];
        }
    }
}

// ---------------- fused conv1->gcnW->conv2 as one K=320 MFMA GEMM ----------------
// z[t,n,:] = sum_{m=0..4} x[t+m-2,n,:] @ W5cls_m + bz_cls   (bf16 out)
// grid: (nb, t); block = 64 n-rows at one t; 4 waves of 16 rows.
__global__ __launch_bounds__(256) void k_conv5(
    const float* __restrict__ x, const ushort* __restrict__ W5f,
    const float* __restrict__ bz, ushort* __restrict__ z) {
    __shared__ __align__(16) ushort Wl[20480];   // 40 KB; epilogue buf after MFMA

    int tid = threadIdx.x;
    int wv = tid >> 6, lane = tid & 63;
    int ml = lane & 15, q = lane >> 4;
    int t = blockIdx.y;
    int n0 = blockIdx.x * 64;
    int cls = (t == 0) ? 1 : ((t == 63) ? 2 : 0);
    const ushort* Wsrc = W5f + cls * 20480;

    // A fragments: direct global -> registers (lane: row n, K = m*64 + h*32 + q*8 + j)
    int n = n0 + wv * 16 + ml;
    bool nok = (n < N_DIM);
    s8v areg[10];
    #pragma unroll
    for (int m = 0; m < 5; ++m) {
        int ts = t + m - 2;
        bool ok = nok && (ts >= 0) && (ts < T_DIM);
        #pragma unroll
        for (int h = 0; h < 2; ++h) {
            s8v af = {0, 0, 0, 0, 0, 0, 0, 0};
            if (ok) {
                const float* src = x + ((size_t)ts * N_DIM + n) * 64 + h * 32 + q * 8;
                float4 v0 = *(const float4*)src;
                float4 v1 = *(const float4*)(src + 4);
                af[0] = (short)f2b(v0.x); af[1] = (short)f2b(v0.y);
                af[2] = (short)f2b(v0.z); af[3] = (short)f2b(v0.w);
                af[4] = (short)f2b(v1.x); af[5] = (short)f2b(v1.y);
                af[6] = (short)f2b(v1.z); af[7] = (short)f2b(v1.w);
            }
            areg[m * 2 + h] = af;
        }
    }

    // stage W5 class (2560 octets)
    #pragma unroll
    for (int o = 0; o < 10; ++o) {
        int idx = tid + o * 256;
        *(s8v*)&Wl[idx * 8] = *(const s8v*)&Wsrc[idx * 8];
    }
    __syncthreads();

    f4v acc[4];
    #pragma unroll
    for (int c = 0; c < 4; ++c) acc[c] = (f4v){0.f, 0.f, 0.f, 0.f};

    #pragma unroll
    for (int sg = 0; sg < 10; ++sg) {
        #pragma unroll
        for (int c = 0; c < 4; ++c) {
            s8v bf = *(const s8v*)&Wl[((sg * 4 + c) * 64 + lane) * 8];
            acc[c] = __builtin_amdgcn_mfma_f32_16x16x32_bf16(areg[sg], bf, acc[c], 0, 0, 0);
        }
    }

    __syncthreads();   // Wl dead; reuse as epilogue transpose buffer

    ushort* eb = Wl;
    #pragma unroll
    for (int c = 0; c < 4; ++c) {
        int col = c * 16 + ml;
        float bb = bz[cls * 64 + col];
        #pragma unroll
        for (int rg = 0; rg < 4; ++rg) {
            int lrow = wv * 16 + q * 4 + rg;
            eb[lrow * 80 + col] = f2b(acc[c][rg] + bb);
        }
    }
    __syncthreads();
    #pragma unroll
    for (int o = 0; o < 2; ++o) {
        int p = tid + o * 256;
        int r = p >> 3, cc = (p & 7) * 8;
        if (n0 + r < N_DIM)
            *(s8v*)&z[((size_t)t * N_DIM + n0 + r) * 64 + cc] = *(const s8v*)&eb[r * 80 + cc];
    }
}

// ---------------- GCN aggregation (now the LAST linear op): y = Agg(z) + beta ----------------
__global__ __launch_bounds__(256) void k_gather(
    const ushort* __restrict__ zb, const int* __restrict__ offs,
    const int2* __restrict__ edat, const float* __restrict__ beta,
    ushort* __restrict__ yb) {
    int unit = blockIdx.x * 4 + (threadIdx.x >> 6);   // one wave per (t,n)
    int lane = threadIdx.x & 63;
    int g = lane >> 3;            // edge slot 0..7
    int c8 = (lane & 7) * 8;      // channel base
    int t = unit / N_DIM;
    int n = unit - t * N_DIM;
    int cls = (t == 0) ? 1 : ((t == 63) ? 2 : 0);
    int beg = offs[n], end = offs[n + 1];
    const ushort* base = zb + (size_t)t * N_DIM * 64 + c8;

    float a[8] = {0.f, 0.f, 0.f, 0.f, 0.f, 0.f, 0.f, 0.f};
    for (int j = beg + g; j < end; j += 8) {
        int2 e = edat[j];
        float w = __int_as_float(e.y);
        s8v v = *(const s8v*)(base + (size_t)e.x * 64);
        #pragma unroll
        for (int i = 0; i < 8; ++i) a[i] += w * b2f((ushort)v[i]);
    }
    #pragma unroll
    for (int d = 8; d <= 32; d <<= 1)
        #pragma unroll
        for (int i = 0; i < 8; ++i) a[i] += __shfl_xor(a[i], d);

    if (g == 0) {
        s8v pk;
        #pragma unroll
        for (int i = 0; i < 8; ++i) pk[i] = (short)f2b(a[i] + beta[cls * 64 + c8 + i]);
        *(s8v*)&yb[(size_t)unit * 64 + c8] = pk;
    }
}

// ---------------- BN stats over y (bf16) ----------------
__global__ __launch_bounds__(256) void k_ystats(const ushort* __restrict__ yb,
                                                float* __restrict__ bnstats) {
    __shared__ float ssum[64], ssq[64];
    int tid = threadIdx.x;
    if (tid < 64) { ssum[tid] = 0.f; ssq[tid] = 0.f; }
    __syncthreads();
    const int total8 = ROWS * 8;
    int c8 = ((blockIdx.x * 256 + tid) & 7) * 8;   // fixed per thread (stride % 8 == 0)
    float as[8] = {0.f,0.f,0.f,0.f,0.f,0.f,0.f,0.f};
    float aq[8] = {0.f,0.f,0.f,0.f,0.f,0.f,0.f,0.f};
    for (int i8 = blockIdx.x * 256 + tid; i8 < total8; i8 += gridDim.x * 256) {
        s8v v = *(const s8v*)&yb[(size_t)i8 * 8];
        #pragma unroll
        for (int i = 0; i < 8; ++i) {
            float f = b2f((ushort)v[i]);
            as[i] += f;
            aq[i] += f * f;
        }
    }
    #pragma unroll
    for (int i = 0; i < 8; ++i) {
        atomicAdd(&ssum[c8 + i], as[i]);
        atomicAdd(&ssq[c8 + i], aq[i]);
    }
    __syncthreads();
    if (tid < 64) {
        atomicAdd(&bnstats[tid], ssum[tid]);
        atomicAdd(&bnstats[64 + tid], ssq[tid]);
    }
}

// ---------------- BN apply + ReLU: y (bf16) -> out (fp32) ----------------
__global__ __launch_bounds__(256) void k_bn(const ushort* __restrict__ yb,
                                            const float* __restrict__ bnstats,
                                            const float* __restrict__ gamma,
                                            const float* __restrict__ beta,
                                            float* __restrict__ out) {
    __shared__ float sscale[64], sshift[64];
    int tid = threadIdx.x;
    if (tid < 64) {
        float m = bnstats[tid] * (1.0f / ROWS);
        float v = bnstats[64 + tid] * (1.0f / ROWS) - m * m;
        float sc = gamma[tid] * rsqrtf(v + BN_EPS);
        sscale[tid] = sc;
        sshift[tid] = beta[tid] - m * sc;
    }
    __syncthreads();
    const int total8 = ROWS * 8;
    for (int i8 = blockIdx.x * 256 + tid; i8 < total8; i8 += gridDim.x * 256) {
        s8v v = *(const s8v*)&yb[(size_t)i8 * 8];
        int c8 = (i8 & 7) * 8;
        float4 o0, o1;
        o0.x = fmaxf(b2f((ushort)v[0]) * sscale[c8 + 0] + sshift[c8 + 0], 0.f);
        o0.y = fmaxf(b2f((ushort)v[1]) * sscale[c8 + 1] + sshift[c8 + 1], 0.f);
        o0.z = fmaxf(b2f((ushort)v[2]) * sscale[c8 + 2] + sshift[c8 + 2], 0.f);
        o0.w = fmaxf(b2f((ushort)v[3]) * sscale[c8 + 3] + sshift[c8 + 3], 0.f);
        o1.x = fmaxf(b2f((ushort)v[4]) * sscale[c8 + 4] + sshift[c8 + 4], 0.f);
        o1.y = fmaxf(b2f((ushort)v[5]) * sscale[c8 + 5] + sshift[c8 + 5], 0.f);
        o1.z = fmaxf(b2f((ushort)v[6]) * sscale[c8 + 6] + sshift[c8 + 6], 0.f);
        o1.w = fmaxf(b2f((ushort)v[7]) * sscale[c8 + 7] + sshift[c8 + 7], 0.f);
        *(float4*)&out[(size_t)i8 * 8]     = o0;
        *(float4*)&out[(size_t)i8 * 8 + 4] = o1;
    }
}

extern "C" void kernel_launch(void* const* d_in, const int* in_sizes, int n_in,
                              void* d_out, int out_size, void* d_ws, size_t ws_size,
                              hipStream_t stream) {
    const float* x   = (const float*)d_in[0];
    const int*   ei  = (const int*)d_in[1];
    const float* c1w = (const float*)d_in[2];
    const float* c1b = (const float*)d_in[3];
    const float* gw  = (const float*)d_in[4];
    const float* gb  = (const float*)d_in[5];
    const float* c2w = (const float*)d_in[6];
    const float* c2b = (const float*)d_in[7];
    const float* bng = (const float*)d_in[8];
    const float* bnb = (const float*)d_in[9];
    float* out = (float*)d_out;

    // workspace layout
    ushort* yb     = (ushort*)d_ws;                       // ROWS*64 bf16 = 16.4 MB
    ushort* W5f    = yb + (size_t)ROWS * 64;              // 3*20480 shorts
    float*  W1p    = (float*)(W5f + 3 * 20480);           // 12288
    float*  b1c    = W1p + 12288;                         // 64
    float*  bz     = b1c + 64;                            // 192
    float*  beta   = bz + 192;                            // 192
    float*  dinv   = beta + 192;                          // 2000
    float*  bnstats= dinv + 2000;                         // 128
    int*    degi   = (int*)(bnstats + 128);               // 2000
    int*    offs   = degi + 2000;                         // 2001
    int*    cursor = offs + 2001;                         // 2000
    int2*   edat   = (int2*)((char*)(cursor + 2000) +
                     (((size_t)(cursor + 2000)) % 8 ? 4 : 0)); // E+N int2

    ushort* zb = (ushort*)d_out;   // bf16 z parked in d_out (dead before k_bn writes)

    hipMemsetAsync(degi, 0, sizeof(int) * N_DIM, stream);
    hipMemsetAsync(bnstats, 0, sizeof(float) * 128, stream);

    k_deg<<<(E_DIM + 255) / 256, 256, 0, stream>>>(ei, degi);
    k_scan<<<1, 1024, 0, stream>>>(degi, offs, dinv, cursor, edat);
    k_fill<<<(E_DIM + 255) / 256, 256, 0, stream>>>(ei, offs, dinv, cursor, edat);
    k_wprep<<<48, 256, 0, stream>>>(c1w, c1b, gw, W1p, b1c);
    k_wprep5<<<16, 256, 0, stream>>>(W1p, b1c, gb, c2b, c2w, W5f, bz, beta);

    // stage 1: fused conv1 -> gcn-linear -> conv2 (K=5 temporal) -> z bf16 (in d_out)
    k_conv5<<<dim3(32, 64), 256, 0, stream>>>(x, W5f, bz, zb);
    // stage 2: GCN aggregation (last linear op) -> y bf16 (ws)
    k_gather<<<ROWS / 4, 256, 0, stream>>>(zb, offs, edat, beta, yb);
    // stage 3: BN stats over y
    k_ystats<<<1024, 256, 0, stream>>>(yb, bnstats);
    // stage 4: BN apply + ReLU -> fp32 out
    k_bn<<<2048, 256, 0, stream>>>(yb, bnstats, bng, bnb, out);
}

// Round 3
// 230.726 us; speedup vs baseline: 1.1968x; 1.1968x over previous
//
#include <hip/hip_runtime.h>

#define T_DIM 64
#define N_DIM 2000
#define C_DIM 64
#define E_DIM 32000
#define ROWS (T_DIM * N_DIM)   // 128000
#define BN_EPS 1e-5f
#define TCHUNK 4

typedef short s8v __attribute__((ext_vector_type(8)));
typedef float f4v __attribute__((ext_vector_type(4)));

__device__ __forceinline__ ushort f2b(float f) {
    unsigned u = __float_as_uint(f);
    unsigned r = u + 0x7FFF + ((u >> 16) & 1);
    return (ushort)(r >> 16);
}
__device__ __forceinline__ float b2f(ushort h) {
    return __uint_as_float(((unsigned)h) << 16);
}
__device__ __forceinline__ s8v pack8(float4 a, float4 b) {
    s8v r;
    r[0] = (short)f2b(a.x); r[1] = (short)f2b(a.y);
    r[2] = (short)f2b(a.z); r[3] = (short)f2b(a.w);
    r[4] = (short)f2b(b.x); r[5] = (short)f2b(b.y);
    r[6] = (short)f2b(b.z); r[7] = (short)f2b(b.w);
    return r;
}

// ---------------- prep kernels ----------------

__global__ void k_deg(const int* __restrict__ ei, int* __restrict__ deg) {
    int e = blockIdx.x * 256 + threadIdx.x;
    if (e < E_DIM) atomicAdd(&deg[ei[E_DIM + e]], 1);
}

// exclusive prefix sum of (deg[n]+1) -> offs[0..N_DIM], plus fused dinv,
// self-edge slot-0 write, and cursor init.
__global__ void k_scan(const int* __restrict__ deg, int* __restrict__ offs,
                       float* __restrict__ dinv, int* __restrict__ cursor,
                       int2* __restrict__ edat) {
    __shared__ int a[2048], b[2048];
    int tid = threadIdx.x;
    for (int i = tid; i < 2048; i += 1024) a[i] = (i < N_DIM) ? (deg[i] + 1) : 0;
    __syncthreads();
    int* s = a; int* d = b;
    for (int off = 1; off < 2048; off <<= 1) {
        for (int i = tid; i < 2048; i += 1024)
            d[i] = s[i] + ((i >= off) ? s[i - off] : 0);
        __syncthreads();
        int* t = s; s = d; d = t;
    }
    for (int i = tid; i < 2048; i += 1024)
        if (i <= N_DIM) offs[i] = (i == 0) ? 0 : s[i - 1];
    for (int n = tid; n < N_DIM; n += 1024) {
        float dn = rsqrtf((float)(deg[n] + 1));  // +1 self-loop
        dinv[n] = dn;
        int o = (n == 0) ? 0 : s[n - 1];
        edat[o] = make_int2(n, __float_as_int(dn * dn));
        cursor[n] = 1;
    }
}

__global__ void k_fill(const int* __restrict__ ei, const int* __restrict__ offs,
                       const float* __restrict__ dinv, int* __restrict__ cursor,
                       int2* __restrict__ edat) {
    int e = blockIdx.x * 256 + threadIdx.x;
    if (e < E_DIM) {
        int s = ei[e];
        int d = ei[E_DIM + e];
        int p = atomicAdd(&cursor[d], 1);
        edat[offs[d] + p] = make_int2(s, __float_as_int(dinv[s] * dinv[d]));
    }
}

// ---------------- merged weight prep (one launch) ----------------
// Per block i (64 blocks): G[j][c] = (C1_j @ gw)[i,c]; d[j][k] = G_j^T . C2_k rows.
// W5f (cls0 = interior, all (j,k)) in B-frag order for K=320: kk = m*64+i,
//   flat(kk,n) = (((kk>>5)*4 + (n>>4))*64 + ((kk>>3)&3)*16 + (n&15))*8 + (kk&7)
// Correction mats (NEGATED): Wc[0] = -d[2][0] (for t=0), Wc[1] = -d[0][2] (t=63),
//   K=64 frag layout flat(i,n).
// Biases: bz[cls][n], beta[cls][n] (cls0 all k, cls1 skip k=0, cls2 skip k=2).
__global__ __launch_bounds__(256) void k_w(
    const float* __restrict__ c1w, const float* __restrict__ c1b,
    const float* __restrict__ gw, const float* __restrict__ gb,
    const float* __restrict__ c2b, const float* __restrict__ c2w,
    ushort* __restrict__ W5f, ushort* __restrict__ Wc,
    float* __restrict__ bz, float* __restrict__ beta) {
    __shared__ float Gl[3][64];
    __shared__ float b1l[64], gbl[64];
    int i = blockIdx.x, tid = threadIdx.x;
    if (tid < 192) {
        int j = tid >> 6, c = tid & 63;
        float s = 0.f;
        for (int o = 0; o < 64; ++o)
            s += c1w[o * 192 + i * 3 + j] * gw[o * 64 + c];
        Gl[j][c] = s;
    } else {
        int c = tid - 192;
        float s = 0.f;
        if (i == 0)
            for (int o = 0; o < 64; ++o) s += c1b[o] * gw[o * 64 + c];
        b1l[c] = s;
        gbl[c] = gb[c];
    }
    __syncthreads();
    if (tid < 64) {
        int n = tid;
        float d00 = 0.f, d01 = 0.f, d02 = 0.f;
        float d10 = 0.f, d11 = 0.f, d12 = 0.f;
        float d20 = 0.f, d21 = 0.f, d22 = 0.f;
        for (int c = 0; c < 64; ++c) {
            float a0 = Gl[0][c], a1 = Gl[1][c], a2 = Gl[2][c];
            float b0 = c2w[n * 192 + c * 3 + 0];
            float b1 = c2w[n * 192 + c * 3 + 1];
            float b2 = c2w[n * 192 + c * 3 + 2];
            d00 += a0 * b0; d01 += a0 * b1; d02 += a0 * b2;
            d10 += a1 * b0; d11 += a1 * b1; d12 += a1 * b2;
            d20 += a2 * b0; d21 += a2 * b1; d22 += a2 * b2;
        }
        float wm[5];
        wm[0] = d00;
        wm[1] = d01 + d10;
        wm[2] = d02 + d11 + d20;
        wm[3] = d12 + d21;
        wm[4] = d22;
        for (int m = 0; m < 5; ++m) {
            int kk = m * 64 + i;
            int flat = (((kk >> 5) * 4 + (n >> 4)) * 64 + ((kk >> 3) & 3) * 16 + (n & 15)) * 8 + (kk & 7);
            W5f[flat] = f2b(wm[m]);
        }
        int fc = (((i >> 5) * 4 + (n >> 4)) * 64 + ((i >> 3) & 3) * 16 + (n & 15)) * 8 + (i & 7);
        Wc[fc] = f2b(-d20);
        Wc[4096 + fc] = f2b(-d02);
        if (i == 0) {
            float s1[3] = {0.f, 0.f, 0.f}, s2[3] = {0.f, 0.f, 0.f};
            for (int k = 0; k < 3; ++k)
                for (int c = 0; c < 64; ++c) {
                    float w2 = c2w[n * 192 + c * 3 + k];
                    s1[k] += b1l[c] * w2;
                    s2[k] += gbl[c] * w2;
                }
            bz[n]        = s1[0] + s1[1] + s1[2];
            bz[64 + n]   = s1[1] + s1[2];
            bz[128 + n]  = s1[0] + s1[1];
            float cb = c2b[n];
            beta[n]       = s2[0] + s2[1] + s2[2] + cb;
            beta[64 + n]  = s2[1] + s2[2] + cb;
            beta[128 + n] = s2[0] + s2[1] + cb;
        }
    }
}

// ---------------- fused conv (K=320) with rolling t-window ----------------
// Block (nb, tc): rows n0..n0+63, t in [tc*4, tc*4+4). Rolling register window of
// x slices (each slice loaded once). W in LDS across all phases. Boundary t=0/63
// corrected with extra MFMAs against negated Wc. Wave-local epilogue (no barriers
// inside the t-loop).
__global__ __launch_bounds__(256) void k_conv5(
    const float* __restrict__ x, const ushort* __restrict__ W5f,
    const ushort* __restrict__ Wcg, const float* __restrict__ bz,
    ushort* __restrict__ z) {
    __shared__ __align__(16) ushort Wl[20480];      // 40 KB
    __shared__ __align__(16) ushort Cl[4096];       // 8 KB corr
    __shared__ __align__(16) ushort Eb[4][1280];    // 10 KB epilogue (per wave)

    int tid = threadIdx.x, wv = tid >> 6, lane = tid & 63;
    int ml = lane & 15, q = lane >> 4;
    int n0 = blockIdx.x * 64;
    int t0 = blockIdx.y * TCHUNK;
    int n = n0 + wv * 16 + ml;
    bool nok = (n < N_DIM);
    const float* xrow = x + (size_t)n * 64 + q * 8;

    // stage W (2560 16B octets)
    #pragma unroll
    for (int o = 0; o < 10; ++o) {
        int idx = tid + o * 256;
        *(s8v*)&Wl[idx * 8] = *(const s8v*)&W5f[idx * 8];
    }
    bool bnd0 = (t0 == 0), bnd1 = (t0 + TCHUNK == T_DIM);
    if (bnd0 || bnd1) {
        const ushort* src = Wcg + (bnd1 ? 4096 : 0);
        #pragma unroll
        for (int o = 0; o < 2; ++o) {
            int idx = tid + o * 256;
            *(s8v*)&Cl[idx * 8] = *(const s8v*)&src[idx * 8];
        }
    }

    const s8v ZV = {0, 0, 0, 0, 0, 0, 0, 0};
    s8v a[16];
    #pragma unroll
    for (int i = 0; i < 16; ++i) a[i] = ZV;

    // preload slices t0-2 .. t0+2 -> a[0..9]
    #pragma unroll
    for (int i = 0; i < 5; ++i) {
        int s = t0 - 2 + i;
        if (nok && s >= 0 && s < T_DIM) {
            const float* p = xrow + (size_t)s * N_DIM * 64;
            float4 v0 = *(const float4*)p;
            float4 v1 = *(const float4*)(p + 4);
            float4 v2 = *(const float4*)(p + 32);
            float4 v3 = *(const float4*)(p + 36);
            a[2 * i]     = pack8(v0, v1);
            a[2 * i + 1] = pack8(v2, v3);
        }
    }
    __syncthreads();   // W ready

    #pragma unroll
    for (int p = 0; p < TCHUNK; ++p) {
        int t = t0 + p;
        // prefetch slice t0+3+p (consumed next phase)
        float4 r0, r1, r2, r3;
        bool pf = false;
        if (p < TCHUNK - 1) {
            int s = t0 + 3 + p;
            if (nok && s < T_DIM) {
                pf = true;
                const float* pp = xrow + (size_t)s * N_DIM * 64;
                r0 = *(const float4*)pp;
                r1 = *(const float4*)(pp + 4);
                r2 = *(const float4*)(pp + 32);
                r3 = *(const float4*)(pp + 36);
            }
        }

        f4v acc[4];
        #pragma unroll
        for (int c = 0; c < 4; ++c) acc[c] = (f4v){0.f, 0.f, 0.f, 0.f};

        #pragma unroll
        for (int sg = 0; sg < 10; ++sg) {
            #pragma unroll
            for (int c = 0; c < 4; ++c) {
                s8v bf = *(const s8v*)&Wl[((sg * 4 + c) * 64 + lane) * 8];
                acc[c] = __builtin_amdgcn_mfma_f32_16x16x32_bf16(a[2 * p + sg], bf, acc[c], 0, 0, 0);
            }
        }
        if (bnd0 && p == 0) {           // t == 0: subtract d[2][0] . x[0]  (x[0] = a[4],a[5])
            #pragma unroll
            for (int s2 = 0; s2 < 2; ++s2)
                #pragma unroll
                for (int c = 0; c < 4; ++c) {
                    s8v bf = *(const s8v*)&Cl[((s2 * 4 + c) * 64 + lane) * 8];
                    acc[c] = __builtin_amdgcn_mfma_f32_16x16x32_bf16(a[4 + s2], bf, acc[c], 0, 0, 0);
                }
        }
        if (bnd1 && p == TCHUNK - 1) {  // t == 63: subtract d[0][2] . x[63] (x[63] = a[10],a[11])
            #pragma unroll
            for (int s2 = 0; s2 < 2; ++s2)
                #pragma unroll
                for (int c = 0; c < 4; ++c) {
                    s8v bf = *(const s8v*)&Cl[((s2 * 4 + c) * 64 + lane) * 8];
                    acc[c] = __builtin_amdgcn_mfma_f32_16x16x32_bf16(a[10 + s2], bf, acc[c], 0, 0, 0);
                }
        }

        int cls = (bnd0 && p == 0) ? 1 : ((bnd1 && p == TCHUNK - 1) ? 2 : 0);
        // wave-local epilogue transpose (no cross-wave deps -> no barrier)
        ushort* eb = &Eb[wv][0];
        #pragma unroll
        for (int c = 0; c < 4; ++c) {
            int col = c * 16 + ml;
            float bb = bz[cls * 64 + col];
            #pragma unroll
            for (int rg = 0; rg < 4; ++rg)
                eb[(q * 4 + rg) * 80 + col] = f2b(acc[c][rg] + bb);
        }
        int rr = lane >> 2, cof = (lane & 3) * 16;
        int gn = n0 + wv * 16 + rr;
        if (gn < N_DIM) {
            ushort* dst = &z[((size_t)t * N_DIM + gn) * 64 + cof];
            *(s8v*)dst       = *(const s8v*)&eb[rr * 80 + cof];
            *(s8v*)(dst + 8) = *(const s8v*)&eb[rr * 80 + cof + 8];
        }
        // convert prefetched slice into the window
        if (p < TCHUNK - 1) {
            a[10 + 2 * p] = pf ? pack8(r0, r1) : ZV;
            a[11 + 2 * p] = pf ? pack8(r2, r3) : ZV;
        }
    }
}

// ---------------- GCN aggregation (last linear op): y = Agg(z) + beta ----------------
// XCD-aware swizzle: each XCD owns a contiguous band of 8 t-values so each
// z t-slab is fetched into exactly one XCD's L2.
__global__ __launch_bounds__(256) void k_gather(
    const ushort* __restrict__ zb, const int* __restrict__ offs,
    const int2* __restrict__ edat, const float* __restrict__ beta,
    ushort* __restrict__ yb) {
    int bid = blockIdx.x;
    int cpx = gridDim.x >> 3;                       // blocks per XCD
    int swz = (bid & 7) * cpx + (bid >> 3);
    int unit = swz * 4 + (threadIdx.x >> 6);        // one wave per (t,n)
    int lane = threadIdx.x & 63;
    int g = lane >> 3;            // edge slot 0..7
    int c8 = (lane & 7) * 8;      // channel base
    int t = unit / N_DIM;
    int n = unit - t * N_DIM;
    int cls = (t == 0) ? 1 : ((t == 63) ? 2 : 0);
    int beg = offs[n], end = offs[n + 1];
    const ushort* base = zb + (size_t)t * N_DIM * 64 + c8;

    float a[8] = {0.f, 0.f, 0.f, 0.f, 0.f, 0.f, 0.f, 0.f};
    for (int j = beg + g; j < end; j += 8) {
        int2 e = edat[j];
        float w = __int_as_float(e.y);
        s8v v = *(const s8v*)(base + (size_t)e.x * 64);
        #pragma unroll
        for (int i = 0; i < 8; ++i) a[i] += w * b2f((ushort)v[i]);
    }
    #pragma unroll
    for (int d = 8; d <= 32; d <<= 1)
        #pragma unroll
        for (int i = 0; i < 8; ++i) a[i] += __shfl_xor(a[i], d);

    if (g == 0) {
        s8v pk;
        #pragma unroll
        for (int i = 0; i < 8; ++i) pk[i] = (short)f2b(a[i] + beta[cls * 64 + c8 + i]);
        *(s8v*)&yb[(size_t)unit * 64 + c8] = pk;
    }
}

// ---------------- BN stats over y (bf16) ----------------
__global__ __launch_bounds__(256) void k_ystats(const ushort* __restrict__ yb,
                                                float* __restrict__ bnstats) {
    __shared__ float ssum[64], ssq[64];
    int tid = threadIdx.x;
    if (tid < 64) { ssum[tid] = 0.f; ssq[tid] = 0.f; }
    __syncthreads();
    const int total8 = ROWS * 8;
    int c8 = ((blockIdx.x * 256 + tid) & 7) * 8;   // fixed per thread (stride % 8 == 0)
    float as[8] = {0.f,0.f,0.f,0.f,0.f,0.f,0.f,0.f};
    float aq[8] = {0.f,0.f,0.f,0.f,0.f,0.f,0.f,0.f};
    for (int i8 = blockIdx.x * 256 + tid; i8 < total8; i8 += gridDim.x * 256) {
        s8v v = *(const s8v*)&yb[(size_t)i8 * 8];
        #pragma unroll
        for (int i = 0; i < 8; ++i) {
            float f = b2f((ushort)v[i]);
            as[i] += f;
            aq[i] += f * f;
        }
    }
    #pragma unroll
    for (int i = 0; i < 8; ++i) {
        atomicAdd(&ssum[c8 + i], as[i]);
        atomicAdd(&ssq[c8 + i], aq[i]);
    }
    __syncthreads();
    if (tid < 64) {
        atomicAdd(&bnstats[tid], ssum[tid]);
        atomicAdd(&bnstats[64 + tid], ssq[tid]);
    }
}

// ---------------- BN apply + ReLU: y (bf16) -> out (fp32) ----------------
__global__ __launch_bounds__(256) void k_bn(const ushort* __restrict__ yb,
                                            const float* __restrict__ bnstats,
                                            const float* __restrict__ gamma,
                                            const float* __restrict__ beta,
                                            float* __restrict__ out) {
    __shared__ float sscale[64], sshift[64];
    int tid = threadIdx.x;
    if (tid < 64) {
        float m = bnstats[tid] * (1.0f / ROWS);
        float v = bnstats[64 + tid] * (1.0f / ROWS) - m * m;
        float sc = gamma[tid] * rsqrtf(v + BN_EPS);
        sscale[tid] = sc;
        sshift[tid] = beta[tid] - m * sc;
    }
    __syncthreads();
    const int total8 = ROWS * 8;
    for (int i8 = blockIdx.x * 256 + tid; i8 < total8; i8 += gridDim.x * 256) {
        s8v v = *(const s8v*)&yb[(size_t)i8 * 8];
        int c8 = (i8 & 7) * 8;
        float4 o0, o1;
        o0.x = fmaxf(b2f((ushort)v[0]) * sscale[c8 + 0] + sshift[c8 + 0], 0.f);
        o0.y = fmaxf(b2f((ushort)v[1]) * sscale[c8 + 1] + sshift[c8 + 1], 0.f);
        o0.z = fmaxf(b2f((ushort)v[2]) * sscale[c8 + 2] + sshift[c8 + 2], 0.f);
        o0.w = fmaxf(b2f((ushort)v[3]) * sscale[c8 + 3] + sshift[c8 + 3], 0.f);
        o1.x = fmaxf(b2f((ushort)v[4]) * sscale[c8 + 4] + sshift[c8 + 4], 0.f);
        o1.y = fmaxf(b2f((ushort)v[5]) * sscale[c8 + 5] + sshift[c8 + 5], 0.f);
        o1.z = fmaxf(b2f((ushort)v[6]) * sscale[c8 + 6] + sshift[c8 + 6], 0.f);
        o1.w = fmaxf(b2f((ushort)v[7]) * sscale[c8 + 7] + sshift[c8 + 7], 0.f);
        *(float4*)&out[(size_t)i8 * 8]     = o0;
        *(float4*)&out[(size_t)i8 * 8 + 4] = o1;
    }
}

extern "C" void kernel_launch(void* const* d_in, const int* in_sizes, int n_in,
                              void* d_out, int out_size, void* d_ws, size_t ws_size,
                              hipStream_t stream) {
    const float* x   = (const float*)d_in[0];
    const int*   ei  = (const int*)d_in[1];
    const float* c1w = (const float*)d_in[2];
    const float* c1b = (const float*)d_in[3];
    const float* gw  = (const float*)d_in[4];
    const float* gb  = (const float*)d_in[5];
    const float* c2w = (const float*)d_in[6];
    const float* c2b = (const float*)d_in[7];
    const float* bng = (const float*)d_in[8];
    const float* bnb = (const float*)d_in[9];
    float* out = (float*)d_out;

    // workspace layout
    ushort* yb     = (ushort*)d_ws;                       // ROWS*64 bf16 = 16.4 MB
    ushort* W5f    = yb + (size_t)ROWS * 64;              // 20480 shorts
    ushort* Wc     = W5f + 20480;                         // 2*4096 shorts
    float*  bz     = (float*)(Wc + 8192);                 // 192
    float*  beta   = bz + 192;                            // 192
    float*  dinv   = beta + 192;                          // 2000
    int*    degi   = (int*)(dinv + 2000);                 // 2000  } one memset
    float*  bnstats= (float*)(degi + 2000);               // 128   } (adjacent)
    int*    offs   = (int*)(bnstats + 128);               // 2001
    int*    cursor = offs + 2001;                         // 2000
    int2*   edat   = (int2*)((char*)(cursor + 2000) +
                     (((size_t)(cursor + 2000)) % 8 ? 4 : 0)); // E+N int2

    ushort* zb = (ushort*)d_out;   // bf16 z parked in d_out (dead before k_bn writes)

    hipMemsetAsync(degi, 0, sizeof(int) * N_DIM + sizeof(float) * 128, stream);

    k_deg<<<(E_DIM + 255) / 256, 256, 0, stream>>>(ei, degi);
    k_scan<<<1, 1024, 0, stream>>>(degi, offs, dinv, cursor, edat);
    k_fill<<<(E_DIM + 255) / 256, 256, 0, stream>>>(ei, offs, dinv, cursor, edat);
    k_w<<<64, 256, 0, stream>>>(c1w, c1b, gw, gb, c2b, c2w, W5f, Wc, bz, beta);

    // stage 1: fused conv1 -> gcn-linear -> conv2 (K=5 temporal, t-loop) -> z bf16 (d_out)
    k_conv5<<<dim3(32, T_DIM / TCHUNK), 256, 0, stream>>>(x, W5f, Wc, bz, zb);
    // stage 2: GCN aggregation (XCD-banded) -> y bf16 (ws)
    k_gather<<<ROWS / 4, 256, 0, stream>>>(zb, offs, edat, beta, yb);
    // stage 3: BN stats over y
    k_ystats<<<1024, 256, 0, stream>>>(yb, bnstats);
    // stage 4: BN apply + ReLU -> fp32 out
    k_bn<<<2048, 256, 0, stream>>>(yb, bnstats, bng, bnb, out);
}